// Round 1
// baseline (5341.753 us; speedup 1.0000x reference)
//
#include <hip/hip_runtime.h>
#include <hip/hip_bf16.h>
#include <stdint.h>

// SimpleRNN: x(B,S) int32, state(1,B,H) f32, W_ih(H,V), W_hh(H,H), b_ih(H), b_hh(H),
//            fc_W(V,H), fc_b(V)  ->  ans(S,B,V) f32, h_last(1,B,H) f32
#define VV 8192
#define HH 1024
#define BB 64
#define SS 256

typedef __attribute__((ext_vector_type(8))) short short8;
typedef __attribute__((ext_vector_type(8))) unsigned short ushort8;
typedef __attribute__((ext_vector_type(4))) float f32x4;
typedef __attribute__((ext_vector_type(4))) unsigned short ushort4v;

__device__ inline unsigned short f2bf(float f) {
  // round-to-nearest-even f32 -> bf16 bits
  uint32_t u = __float_as_uint(f);
  uint32_t r = (u + 0x7fffu + ((u >> 16) & 1u)) >> 16;
  return (unsigned short)r;
}

__device__ inline short8 as_s8(ushort8 u) {
  union { ushort8 u; short8 s; } x; x.u = u; return x.s;
}

// ---------------- prep: hT0 (H,B) from state, xT (S,B) from x, eb = b_ih+b_hh ----
__global__ __launch_bounds__(256) void prep_kernel(
    const float* __restrict__ state, const int* __restrict__ x,
    const float* __restrict__ b_ih, const float* __restrict__ b_hh,
    float* __restrict__ hT0, int* __restrict__ xT, float* __restrict__ eb)
{
  int idx = blockIdx.x * 256 + threadIdx.x;
  if (idx < BB * HH) {                       // hT0[j*64+b] = state[b*H + j]
    int j = idx >> 6, b = idx & 63;
    hT0[idx] = state[b * HH + j];
  } else if (idx < BB * HH + SS * BB) {      // xT[s*64+b] = x[b*S + s]
    int k = idx - BB * HH;
    int s = k >> 6, b = k & 63;
    xT[k] = x[b * SS + s];
  } else if (idx < BB * HH + SS * BB + HH) { // eb[i]
    int i = idx - (BB * HH + SS * BB);
    eb[i] = b_ih[i] + b_hh[i];
  }
}

// ---------------- fc_W f32 -> bf16 bits ----------------
__global__ __launch_bounds__(256) void convw_kernel(const float* __restrict__ w,
                                                    unsigned short* __restrict__ wb)
{
  const int64_t n4 = (int64_t)VV * HH / 4;
  for (int64_t p = blockIdx.x * 256 + threadIdx.x; p < n4;
       p += (int64_t)gridDim.x * 256) {
    float4 f = ((const float4*)w)[p];
    ushort4v o;
    o.x = f2bf(f.x); o.y = f2bf(f.y); o.z = f2bf(f.z); o.w = f2bf(f.w);
    ((ushort4v*)wb)[p] = o;
  }
}

// ---------------- one recurrence step ----------------
// grid 256 WGs x 256 thr. WG g owns rows i in [4g, 4g+4). wave = 64 lanes over b.
// h stored transposed hT[j][b] (H x B) f32 so lane reads coalesce; W_hh[i][j] is
// wave-uniform (readfirstlane -> s_load). Embedding gathered on the fly.
__global__ __launch_bounds__(256) void rnn_step_kernel(
    const float* __restrict__ hin, float* __restrict__ hout,
    const float* __restrict__ W_hh, const float* __restrict__ W_ih,
    const int* __restrict__ xT, const float* __restrict__ eb,
    unsigned short* __restrict__ y, int s)
{
  __shared__ float buf[128 * 64];            // 32 KiB chunk of hT
  const int t = threadIdx.x;
  const int b = t & 63;
  const int i = (blockIdx.x << 2) + (t >> 6);
  const int iu = __builtin_amdgcn_readfirstlane(i);
  const float* __restrict__ wrow = W_hh + (size_t)iu * HH;
  float acc = 0.f;
  for (int c = 0; c < 8; ++c) {
    const float4* src = (const float4*)(hin + c * 128 * 64);
    float4* dst = (float4*)buf;
    __syncthreads();
#pragma unroll
    for (int q = 0; q < 8; ++q) dst[t + q * 256] = src[t + q * 256];
    __syncthreads();
    const float* __restrict__ wc_ = wrow + c * 128;
#pragma unroll 16
    for (int jj = 0; jj < 128; ++jj)
      acc += buf[jj * 64 + b] * wc_[jj];     // buf: 2-way bank alias (free); wc_: s_load
  }
  const int xv = xT[s * 64 + b];
  const float embv = W_ih[(size_t)iu * VV + xv] + eb[iu];
  const float h = tanhf(acc + embv);
  hout[i * 64 + b] = h;                               // transposed for next step
  y[(size_t)(s * 64 + b) * HH + i] = f2bf(h);         // row-major bf16 for GEMM
}

// ---------------- output GEMM: C(16384,8192) = y(16384,1024) @ fcW(8192,1024)^T + b
// 128x128 tile, BK=32, 4 waves in 2x2, each wave 64x64 via 4x4 frags of 16x16x32.
__global__ __launch_bounds__(256) void gemm_kernel(
    const unsigned short* __restrict__ A,   // (16384,1024) bf16 bits
    const unsigned short* __restrict__ Bm,  // (8192,1024) bf16 bits
    const float* __restrict__ bias,         // (8192)
    float* __restrict__ C)                  // (16384,8192) f32
{
  constexpr int K = HH;
  __shared__ unsigned short As[128 * 32];   // 8 KiB
  __shared__ unsigned short Bs[128 * 32];   // 8 KiB
  const int t = threadIdx.x;
  const int lane = t & 63;
  const int wid = t >> 6;
  const int wr = wid >> 1, wc = wid & 1;
  const int lrow = lane & 15;               // frag row/col index
  const int kq = lane >> 4;                 // 0..3: k-group (k = kq*8 + e)
  const int bm = blockIdx.y, bn = blockIdx.x;

  // staging: thread t covers tile row t>>1, cols (t&1)*16 .. +16 (two ushort8)
  const int ar0 = t >> 1;
  const int ac0 = (t & 1) * 16;
  const unsigned short* Arow = A + (size_t)(bm * 128 + ar0) * K + ac0;
  const unsigned short* Brow = Bm + (size_t)(bn * 128 + ar0) * K + ac0;

  f32x4 acc[4][4] = {};
  ushort8 ra0 = *(const ushort8*)(Arow);
  ushort8 ra1 = *(const ushort8*)(Arow + 8);
  ushort8 rb0 = *(const ushort8*)(Brow);
  ushort8 rb1 = *(const ushort8*)(Brow + 8);

  for (int kt = 0; kt < 32; ++kt) {
    __syncthreads();
    *(ushort8*)(&As[ar0 * 32 + ac0]) = ra0;
    *(ushort8*)(&As[ar0 * 32 + ac0 + 8]) = ra1;
    *(ushort8*)(&Bs[ar0 * 32 + ac0]) = rb0;
    *(ushort8*)(&Bs[ar0 * 32 + ac0 + 8]) = rb1;
    __syncthreads();
    if (kt < 31) {                          // prefetch next K-tile into regs
      const unsigned short* An = Arow + (kt + 1) * 32;
      const unsigned short* Bn = Brow + (kt + 1) * 32;
      ra0 = *(const ushort8*)(An); ra1 = *(const ushort8*)(An + 8);
      rb0 = *(const ushort8*)(Bn); rb1 = *(const ushort8*)(Bn + 8);
    }
    short8 fa[4], fb[4];
#pragma unroll
    for (int mt = 0; mt < 4; ++mt)
      fa[mt] = as_s8(*(const ushort8*)(&As[(wr * 64 + mt * 16 + lrow) * 32 + kq * 8]));
#pragma unroll
    for (int nt = 0; nt < 4; ++nt)
      fb[nt] = as_s8(*(const ushort8*)(&Bs[(wc * 64 + nt * 16 + lrow) * 32 + kq * 8]));
#pragma unroll
    for (int mt = 0; mt < 4; ++mt)
#pragma unroll
      for (int nt = 0; nt < 4; ++nt)
        acc[mt][nt] = __builtin_amdgcn_mfma_f32_16x16x32_bf16(
            fa[mt], fb[nt], acc[mt][nt], 0, 0, 0);
  }

  const int crow0 = bm * 128 + wr * 64;
  const int ccol0 = bn * 128 + wc * 64;
#pragma unroll
  for (int mt = 0; mt < 4; ++mt) {
#pragma unroll
    for (int nt = 0; nt < 4; ++nt) {
      const int col = ccol0 + nt * 16 + lrow;
      const float bv = bias[col];
#pragma unroll
      for (int r = 0; r < 4; ++r) {
        const int row = crow0 + mt * 16 + kq * 4 + r;   // D: col=lane&15, row=(lane>>4)*4+r
        C[(size_t)row * VV + col] = acc[mt][nt][r] + bv;
      }
    }
  }
}

// ---------------- final state un-transpose ----------------
__global__ __launch_bounds__(256) void state_kernel(const float* __restrict__ hT,
                                                    float* __restrict__ o)
{
  int idx = blockIdx.x * 256 + threadIdx.x;   // 65536
  int b = idx >> 10, i = idx & 1023;
  o[idx] = hT[i * 64 + b];
}

extern "C" void kernel_launch(void* const* d_in, const int* in_sizes, int n_in,
                              void* d_out, int out_size, void* d_ws, size_t ws_size,
                              hipStream_t stream)
{
  const int*   x     = (const int*)d_in[0];
  const float* state = (const float*)d_in[1];
  const float* W_ih  = (const float*)d_in[2];
  const float* W_hh  = (const float*)d_in[3];
  const float* b_ih  = (const float*)d_in[4];
  const float* b_hh  = (const float*)d_in[5];
  const float* fc_W  = (const float*)d_in[6];
  const float* fc_b  = (const float*)d_in[7];
  float* out = (float*)d_out;

  char* ws = (char*)d_ws;
  unsigned short* fcWb = (unsigned short*)ws;                    // 16 MiB (V*H bf16)
  unsigned short* y    = (unsigned short*)(ws + (16u << 20));    // 32 MiB (S*B x H bf16)
  float* h0 = (float*)(ws + (48u << 20));                        // 256 KiB hT dbuf
  float* h1 = (float*)(ws + (48u << 20) + BB * HH * 4);
  int*   xT = (int*)(ws + (49u << 20));                          // 64 KiB
  float* eb = (float*)(ws + (49u << 20) + SS * BB * 4);          // 4 KiB

  prep_kernel<<<dim3(324), dim3(256), 0, stream>>>(state, x, b_ih, b_hh, h0, xT, eb);
  convw_kernel<<<dim3(2048), dim3(256), 0, stream>>>(fc_W, fcWb);

  float* hb[2] = { h0, h1 };
  for (int s = 0; s < SS; ++s) {
    rnn_step_kernel<<<dim3(256), dim3(256), 0, stream>>>(
        hb[s & 1], hb[(s + 1) & 1], W_hh, W_ih, xT, eb, y, s);
  }

  gemm_kernel<<<dim3(64, 128), dim3(256), 0, stream>>>(y, fcWb, fc_b, out);
  state_kernel<<<dim3(256), dim3(256), 0, stream>>>(h0, out + (size_t)SS * BB * VV);
}